// Round 2
// baseline (459.329 us; speedup 1.0000x reference)
//
#include <hip/hip_runtime.h>
#include <hip/hip_cooperative_groups.h>
#include <math.h>

namespace cg = cooperative_groups;

// CascadeGCN R18: cooperative fused kernel with occupancy-gated fallback.
// R17's coop launch silently failed (absmax == max|ref|, out never written):
// 512-thread blocks at launch_bounds(512,4) put 512 co-resident blocks
// EXACTLY at the runtime's capacity -> launch rejected. R18 uses 256-thread
// blocks (2/CU needed, 4/CU available = 2x headroom), gates on a host-side
// occupancy query, and falls back to the verified R16 5-kernel pipeline if
// the gate fails. Phases (coop): 0 partition(+global deg atomics) |
// 1 deg scan + xs | 2 LDS sort + layer1 | 3 layer2 from LDS-resident stage2.

#define NB_SHIFT  8          // 256 nodes per bucket
#define BNODES    256
#define NBK       512        // level-1 key space (nb = 391, padded)
#define CAP       8192       // bucket capacity (mean 6400, +22 sigma)
#define CAP_SHIFT 13
#define CHUNK     4888       // 512 chunks over E=2.5M
#define PBLK      256        // coop block: 4 waves (co-residency headroom)
#define GRID      512

struct SMemP0 {                       // partition phase: 37520 B
    int sp[CHUNK];                    // packed records (dlow<<24 | src)
    unsigned short sb[CHUNK];         // bucket ids
    int cnt[NBK], ofs[NBK], cur[NBK], gbase[NBK];
};
struct SMemP1 {                       // bucket phases: 36736 B
    int stage2[CAP];                  // node-sorted src ids (persists ph2->ph3)
    int ofs[BNODES], cnt[BNODES], cur[BNODES];
    float w1[160], bb1[32], w2[32];
};
union SMem { SMemP0 p0; SMemP1 p1; };

__global__ __launch_bounds__(PBLK, 4) void k_fused(
        const int* __restrict__ src, const int* __restrict__ dst, int E,
        const float* __restrict__ x,
        const float* __restrict__ W1, const float* __restrict__ b1,
        const float* __restrict__ W2, const float* __restrict__ b2,
        float* __restrict__ out,
        int* __restrict__ pairs, int* __restrict__ bcur,
        int* __restrict__ deg, float* __restrict__ h2s,
        float* __restrict__ xs, int n, int nb) {
    __shared__ SMem sm;
    cg::grid_group grid = cg::this_grid();
    const int tid = threadIdx.x;
    const int blk = blockIdx.x;
    const int nbase = blk << NB_SHIFT;

    // ---------- phase 0: LDS bucket partition + global degree count ----------
    {
        int base = blk * CHUNK;
        if (base < E) {
            int m = min(CHUNK, E - base);
            sm.p0.cnt[tid] = 0;
            sm.p0.cnt[tid + PBLK] = 0;                // NBK == 2*PBLK
            __syncthreads();
            // pass 1: bucket histogram + per-node degree (fire-and-forget)
            for (int i = tid; i < m; i += 2 * PBLK) {
                int i1 = i + PBLK;
                int d0 = dst[base + i];
                atomicAdd(&sm.p0.cnt[d0 >> NB_SHIFT], 1);
                atomicAdd(&deg[d0], 1);
                if (i1 < m) {
                    int d1 = dst[base + i1];
                    atomicAdd(&sm.p0.cnt[d1 >> NB_SHIFT], 1);
                    atomicAdd(&deg[d1], 1);
                }
            }
            __syncthreads();
            // exclusive scan over NBK=512 keys, 2 per thread (Hillis-Steele)
            int v0 = sm.p0.cnt[tid];
            int v1 = sm.p0.cnt[tid + PBLK];
            sm.p0.ofs[tid] = v0;
            sm.p0.ofs[tid + PBLK] = v1;
            __syncthreads();
            for (int off = 1; off < NBK; off <<= 1) {
                int u0 = (tid >= off) ? sm.p0.ofs[tid - off] : 0;
                int u1 = (tid + PBLK >= off) ? sm.p0.ofs[tid + PBLK - off] : 0;
                __syncthreads();
                sm.p0.ofs[tid] += u0;
                sm.p0.ofs[tid + PBLK] += u1;
                __syncthreads();
            }
            int pre0 = sm.p0.ofs[tid] - v0;
            int pre1 = sm.p0.ofs[tid + PBLK] - v1;
            sm.p0.ofs[tid] = pre0;        sm.p0.cur[tid] = pre0;
            sm.p0.ofs[tid + PBLK] = pre1; sm.p0.cur[tid + PBLK] = pre1;
            sm.p0.gbase[tid] = (tid << CAP_SHIFT)
                             + (v0 ? atomicAdd(&bcur[tid], v0) : 0);
            sm.p0.gbase[tid + PBLK] = ((tid + PBLK) << CAP_SHIFT)
                             + (v1 ? atomicAdd(&bcur[tid + PBLK], v1) : 0);
            __syncthreads();
            // pass 2: bucket-ordered scatter into LDS (4x unrolled)
            for (int i = tid; i < m; i += 4 * PBLK) {
                int ia = i + PBLK, ib = i + 2 * PBLK, ic = i + 3 * PBLK;
                int s0 = src[base + i], d0 = dst[base + i];
                int s1 = 0, d1 = 0, s2 = 0, d2 = 0, s3 = 0, d3 = 0;
                if (ia < m) { s1 = src[base + ia]; d1 = dst[base + ia]; }
                if (ib < m) { s2 = src[base + ib]; d2 = dst[base + ib]; }
                if (ic < m) { s3 = src[base + ic]; d3 = dst[base + ic]; }
                int b0 = d0 >> NB_SHIFT;
                int p0 = atomicAdd(&sm.p0.cur[b0], 1);
                sm.p0.sp[p0] = ((d0 & (BNODES - 1)) << 24) | s0;
                sm.p0.sb[p0] = (unsigned short)b0;
                if (ia < m) {
                    int b1k = d1 >> NB_SHIFT;
                    int p1 = atomicAdd(&sm.p0.cur[b1k], 1);
                    sm.p0.sp[p1] = ((d1 & (BNODES - 1)) << 24) | s1;
                    sm.p0.sb[p1] = (unsigned short)b1k;
                }
                if (ib < m) {
                    int b2k = d2 >> NB_SHIFT;
                    int p2 = atomicAdd(&sm.p0.cur[b2k], 1);
                    sm.p0.sp[p2] = ((d2 & (BNODES - 1)) << 24) | s2;
                    sm.p0.sb[p2] = (unsigned short)b2k;
                }
                if (ic < m) {
                    int b3k = d3 >> NB_SHIFT;
                    int p3 = atomicAdd(&sm.p0.cur[b3k], 1);
                    sm.p0.sp[p3] = ((d3 & (BNODES - 1)) << 24) | s3;
                    sm.p0.sb[p3] = (unsigned short)b3k;
                }
            }
            __syncthreads();
            // coalesced-run writeout
            for (int i = tid; i < m; i += PBLK) {
                int b = sm.p0.sb[i];
                pairs[sm.p0.gbase[b] + (i - sm.p0.ofs[b])] = sm.p0.sp[i];
            }
        }
    }
    grid.sync();   // pairs + bcur + deg complete

    // ---------- phase 1: per-node offsets (LDS scan of deg) + scaled x ----------
    if (blk < nb) {
        if (tid < 160) sm.p1.w1[tid] = W1[tid];
        else if (tid < 192) sm.p1.bb1[tid - 160] = b1[tid - 160];
        else if (tid < 224) sm.p1.w2[tid - 192] = W2[tid - 192];
        int node = nbase + tid;                    // PBLK == BNODES: 1 node/thread
        int v = (node < n) ? deg[node] : 0;
        sm.p1.cnt[tid] = v;
        sm.p1.ofs[tid] = v;
        __syncthreads();
        for (int off = 1; off < BNODES; off <<= 1) {   // Hillis-Steele
            int u = (tid >= off) ? sm.p1.ofs[tid - off] : 0;
            __syncthreads();
            sm.p1.ofs[tid] += u;
            __syncthreads();
        }
        int pre = sm.p1.ofs[tid] - v;               // exclusive
        sm.p1.ofs[tid] = pre;
        sm.p1.cur[tid] = pre;
        if (node < n) {
            float di = rsqrtf((float)v + 1.0f);
            const float* xr = x + (size_t)node * 5;
            float* xo = xs + ((size_t)node << 3);   // padded row: 8 floats
#pragma unroll
            for (int k = 0; k < 5; ++k) xo[k] = xr[k] * di;
        }
    }
    grid.sync();   // xs complete (cross-bucket gathers ahead)

    // ---------- phase 2: LDS counting sort + fused layer-1 aggregation ----------
    if (blk < nb) {
        int base = blk << CAP_SHIFT;
        int len = min(bcur[blk], CAP);
        for (int i = tid; i < len; i += 4 * PBLK) {     // 4x unrolled scatter
            int ia = i + PBLK, ib = i + 2 * PBLK, ic = i + 3 * PBLK;
            int v0 = pairs[base + i];
            int v1 = (ia < len) ? pairs[base + ia] : -1;
            int v2 = (ib < len) ? pairs[base + ib] : -1;
            int v3 = (ic < len) ? pairs[base + ic] : -1;
            int p0 = atomicAdd(&sm.p1.cur[((unsigned)v0) >> 24], 1);
            sm.p1.stage2[p0] = v0 & 0x00FFFFFF;
            if (v1 != -1) {
                int p1 = atomicAdd(&sm.p1.cur[((unsigned)v1) >> 24], 1);
                sm.p1.stage2[p1] = v1 & 0x00FFFFFF;
            }
            if (v2 != -1) {
                int p2 = atomicAdd(&sm.p1.cur[((unsigned)v2) >> 24], 1);
                sm.p1.stage2[p2] = v2 & 0x00FFFFFF;
            }
            if (v3 != -1) {
                int p3 = atomicAdd(&sm.p1.cur[((unsigned)v3) >> 24], 1);
                sm.p1.stage2[p3] = v3 & 0x00FFFFFF;
            }
        }
        __syncthreads();
        // layer-1 aggregation straight from LDS: 2 threads/node, 2 passes
        int half = tid & 1;
        for (int t2 = tid >> 1; t2 < BNODES; t2 += (PBLK >> 1)) {
            int node = nbase + t2;
            if (node >= n) continue;                // pairwise-uniform: shfl safe
            int beg = sm.p1.ofs[t2], dg = sm.p1.cnt[t2];
            float a0 = 0.f, a1 = 0.f, a2 = 0.f, a3 = 0.f, a4 = 0.f;
            if (!half) {                            // self-loop term
                const float* xo = xs + ((size_t)node << 3);
                a0 = xo[0]; a1 = xo[1]; a2 = xo[2]; a3 = xo[3]; a4 = xo[4];
            }
            for (int e = beg + half; e < beg + dg; e += 2) {
                int s = sm.p1.stage2[e];
                const float* xr = xs + ((size_t)s << 3);
                float4 q = *(const float4*)xr;
                float q4 = xr[4];
                a0 += q.x; a1 += q.y; a2 += q.z; a3 += q.w; a4 += q4;
            }
            a0 += __shfl_xor(a0, 1); a1 += __shfl_xor(a1, 1);
            a2 += __shfl_xor(a2, 1); a3 += __shfl_xor(a3, 1);
            a4 += __shfl_xor(a4, 1);
            if (!half) {
                float di = rsqrtf((float)dg + 1.0f);
                a0 *= di; a1 *= di; a2 *= di; a3 *= di; a4 *= di;
                float sum = 0.f;
#pragma unroll
                for (int c = 0; c < 32; ++c) {
                    float z = sm.p1.bb1[c] + a0 * sm.p1.w1[c]
                            + a1 * sm.p1.w1[32 + c] + a2 * sm.p1.w1[64 + c]
                            + a3 * sm.p1.w1[96 + c] + a4 * sm.p1.w1[128 + c];
                    sum += fmaxf(z, 0.f) * sm.p1.w2[c];
                }
                h2s[node] = sum * di;               // pre-scale by src dinv
            }
        }
    }
    grid.sync();   // h2s complete

    // ---------- phase 3: layer-2 from LDS-resident stage2 ----------
    if (blk < nb) {
        int half = tid & 1;
        for (int t2 = tid >> 1; t2 < BNODES; t2 += (PBLK >> 1)) {
            int node = nbase + t2;
            if (node >= n) continue;
            int beg = sm.p1.ofs[t2], dg = sm.p1.cnt[t2];
            float a = 0.f;
            for (int e = beg + half; e < beg + dg; e += 2)
                a += h2s[sm.p1.stage2[e]];
            a += __shfl_xor(a, 1);
            if (!half) {
                float di = rsqrtf((float)dg + 1.0f);
                float vv = di * (a + h2s[node]) + b2[0];
                out[node] = 1.0f / (1.0f + __expf(-vv));
            }
        }
    }
}

// ===================== fallback: verified R16 pipeline =====================

__global__ __launch_bounds__(512) void k_part(const int* __restrict__ src,
                                              const int* __restrict__ dst, int E,
                                              int* __restrict__ bcur,
                                              int* __restrict__ pairs) {
    __shared__ int sp[CHUNK];
    __shared__ unsigned short sb[CHUNK];
    __shared__ int cnt[NBK], ofs[NBK], cur[NBK], gbase[NBK];
    int tid = threadIdx.x;
    int base = blockIdx.x * CHUNK;
    int m = min(CHUNK, E - base);

    if (tid < NBK) cnt[tid] = 0;
    __syncthreads();
    for (int i = tid; i < m; i += 2 * 512) {
        int i1 = i + 512;
        int k0 = dst[base + i] >> NB_SHIFT;
        int k1 = (i1 < m) ? (dst[base + i1] >> NB_SHIFT) : -1;
        atomicAdd(&cnt[k0], 1);
        if (k1 >= 0) atomicAdd(&cnt[k1], 1);
    }
    __syncthreads();
    int v = cnt[tid];
    ofs[tid] = v;
    __syncthreads();
    for (int off = 1; off < NBK; off <<= 1) {
        int u = (tid >= off) ? ofs[tid - off] : 0;
        __syncthreads();
        ofs[tid] += u;
        __syncthreads();
    }
    int pre = ofs[tid] - v;
    ofs[tid] = pre;
    cur[tid] = pre;
    gbase[tid] = (tid << CAP_SHIFT) + (v ? atomicAdd(&bcur[tid], v) : 0);
    __syncthreads();
    for (int i = tid; i < m; i += 4 * 512) {
        int ia = i + 512, ib = i + 1024, ic = i + 1536;
        int s0 = src[base + i], d0 = dst[base + i];
        int s1 = 0, d1 = 0, s2 = 0, d2 = 0, s3 = 0, d3 = 0;
        if (ia < m) { s1 = src[base + ia]; d1 = dst[base + ia]; }
        if (ib < m) { s2 = src[base + ib]; d2 = dst[base + ib]; }
        if (ic < m) { s3 = src[base + ic]; d3 = dst[base + ic]; }
        int b0 = d0 >> NB_SHIFT;
        int p0 = atomicAdd(&cur[b0], 1);
        sp[p0] = ((d0 & (BNODES - 1)) << 24) | s0;
        sb[p0] = (unsigned short)b0;
        if (ia < m) {
            int b1 = d1 >> NB_SHIFT;
            int p1 = atomicAdd(&cur[b1], 1);
            sp[p1] = ((d1 & (BNODES - 1)) << 24) | s1;
            sb[p1] = (unsigned short)b1;
        }
        if (ib < m) {
            int b2 = d2 >> NB_SHIFT;
            int p2 = atomicAdd(&cur[b2], 1);
            sp[p2] = ((d2 & (BNODES - 1)) << 24) | s2;
            sb[p2] = (unsigned short)b2;
        }
        if (ic < m) {
            int b3 = d3 >> NB_SHIFT;
            int p3 = atomicAdd(&cur[b3], 1);
            sp[p3] = ((d3 & (BNODES - 1)) << 24) | s3;
            sb[p3] = (unsigned short)b3;
        }
    }
    __syncthreads();
    for (int i = tid; i < m; i += 512) {
        int b = sb[i];
        pairs[gbase[b] + (i - ofs[b])] = sp[i];
    }
}

__global__ __launch_bounds__(512) void k_sorta(const int* __restrict__ pairs,
                                               const int* __restrict__ bcur,
                                               const float* __restrict__ x,
                                               float* __restrict__ dinv,
                                               float* __restrict__ xs,
                                               int* __restrict__ nofs,
                                               int* __restrict__ deg, int n) {
    __shared__ int cnt[BNODES], scn[BNODES];
    int tid = threadIdx.x;
    int b = blockIdx.x;
    int base = b << CAP_SHIFT;
    int len = min(bcur[b], CAP);

    if (tid < BNODES) cnt[tid] = 0;
    __syncthreads();
    for (int i = tid; i < len; i += 512)
        atomicAdd(&cnt[((unsigned)pairs[base + i]) >> 24], 1);
    __syncthreads();
    int v = (tid < BNODES) ? cnt[tid] : 0;
    if (tid < BNODES) scn[tid] = v;
    __syncthreads();
    for (int off = 1; off < BNODES; off <<= 1) {
        int u = (tid < BNODES && tid >= off) ? scn[tid - off] : 0;
        __syncthreads();
        if (tid < BNODES) scn[tid] += u;
        __syncthreads();
    }
    if (tid < BNODES) {
        int node = (b << NB_SHIFT) + tid;
        if (node < n) {
            nofs[node] = base + scn[tid] - v;
            deg[node] = v;
            float di = rsqrtf((float)v + 1.0f);
            dinv[node] = di;
            const float* xr = x + (size_t)node * 5;
            float* xo = xs + ((size_t)node << 3);
#pragma unroll
            for (int k = 0; k < 5; ++k) xo[k] = xr[k] * di;
        }
    }
}

__global__ __launch_bounds__(512) void k_sortagg1(int* __restrict__ pairs,
                                                  const int* __restrict__ bcur,
                                                  const int* __restrict__ nofs,
                                                  const int* __restrict__ deg,
                                                  const float* __restrict__ xs,
                                                  const float* __restrict__ dinv,
                                                  const float* __restrict__ W1,
                                                  const float* __restrict__ b1,
                                                  const float* __restrict__ W2,
                                                  float* __restrict__ h2s, int n) {
    __shared__ int stage2[CAP];
    __shared__ int ofs[BNODES], cnt[BNODES], cur[BNODES];
    __shared__ float w1[160], bb1[32], w2[32];
    int tid = threadIdx.x;
    int b = blockIdx.x;
    int nbase = b << NB_SHIFT;
    int base = b << CAP_SHIFT;
    int len = min(bcur[b], CAP);

    if (tid < 160) w1[tid] = W1[tid];
    else if (tid < 192) bb1[tid - 160] = b1[tid - 160];
    else if (tid < 224) w2[tid - 192] = W2[tid - 192];
    if (tid < BNODES) {
        int node = nbase + tid;
        int o = 0, c = 0;
        if (node < n) { o = nofs[node] - base; c = deg[node]; }
        ofs[tid] = o; cnt[tid] = c; cur[tid] = o;
    }
    __syncthreads();
    for (int i = tid; i < len; i += 2048) {
        int ia = i + 512, ib = i + 1024, ic = i + 1536;
        int v0 = pairs[base + i];
        int v1 = (ia < len) ? pairs[base + ia] : -1;
        int v2 = (ib < len) ? pairs[base + ib] : -1;
        int v3 = (ic < len) ? pairs[base + ic] : -1;
        int p0 = atomicAdd(&cur[((unsigned)v0) >> 24], 1);
        stage2[p0] = v0 & 0x00FFFFFF;
        if (v1 != -1) {
            int p1 = atomicAdd(&cur[((unsigned)v1) >> 24], 1);
            stage2[p1] = v1 & 0x00FFFFFF;
        }
        if (v2 != -1) {
            int p2 = atomicAdd(&cur[((unsigned)v2) >> 24], 1);
            stage2[p2] = v2 & 0x00FFFFFF;
        }
        if (v3 != -1) {
            int p3 = atomicAdd(&cur[((unsigned)v3) >> 24], 1);
            stage2[p3] = v3 & 0x00FFFFFF;
        }
    }
    __syncthreads();
    {
        int len4 = len >> 2;
        const int4* s4 = (const int4*)stage2;
        int4* p4 = (int4*)(pairs + base);
        for (int i = tid; i < len4; i += 512) p4[i] = s4[i];
        for (int i = (len4 << 2) + tid; i < len; i += 512)
            pairs[base + i] = stage2[i];
    }
    int t2 = tid >> 1, half = tid & 1;
    int node = nbase + t2;
    if (node >= n) return;
    int beg = ofs[t2], dg = cnt[t2];
    float a0 = 0.f, a1 = 0.f, a2 = 0.f, a3 = 0.f, a4 = 0.f;
    if (!half) {
        const float* xo = xs + ((size_t)node << 3);
        a0 = xo[0]; a1 = xo[1]; a2 = xo[2]; a3 = xo[3]; a4 = xo[4];
    }
    for (int e = beg + half; e < beg + dg; e += 2) {
        int s = stage2[e];
        const float* xr = xs + ((size_t)s << 3);
        float4 q = *(const float4*)xr;
        float q4 = xr[4];
        a0 += q.x; a1 += q.y; a2 += q.z; a3 += q.w; a4 += q4;
    }
    a0 += __shfl_xor(a0, 1); a1 += __shfl_xor(a1, 1); a2 += __shfl_xor(a2, 1);
    a3 += __shfl_xor(a3, 1); a4 += __shfl_xor(a4, 1);
    if (half) return;
    float di = dinv[node];
    a0 *= di; a1 *= di; a2 *= di; a3 *= di; a4 *= di;
    float sum = 0.f;
#pragma unroll
    for (int c = 0; c < 32; ++c) {
        float z = bb1[c] + a0 * w1[c] + a1 * w1[32 + c] + a2 * w1[64 + c]
                         + a3 * w1[96 + c] + a4 * w1[128 + c];
        sum += fmaxf(z, 0.f) * w2[c];
    }
    h2s[node] = sum * di;
}

__global__ __launch_bounds__(256) void k_agg2(const int* __restrict__ pairs,
                                              const int* __restrict__ nofs,
                                              const int* __restrict__ deg,
                                              const float* __restrict__ h2s,
                                              const float* __restrict__ dinv,
                                              const float* __restrict__ b2,
                                              float* __restrict__ out, int n) {
    int tid = threadIdx.x;
    int node = blockIdx.x * 64 + (tid >> 2);
    int q = tid & 3;
    if (node >= n) return;
    int beg = nofs[node], dg = deg[node];
    float a = 0.f;
    for (int e = beg + q; e < beg + dg; e += 4) a += h2s[pairs[e]];
    a += __shfl_xor(a, 1);
    a += __shfl_xor(a, 2);
    if (q) return;
    float v = dinv[node] * (a + h2s[node]) + b2[0];
    out[node] = 1.0f / (1.0f + __expf(-v));
}

extern "C" void kernel_launch(void* const* d_in, const int* in_sizes, int n_in,
                              void* d_out, int out_size, void* d_ws, size_t ws_size,
                              hipStream_t stream) {
    const float* x  = (const float*)d_in[0];
    const int*   ei = (const int*)d_in[1];
    const float* W1 = (const float*)d_in[2];
    const float* b1 = (const float*)d_in[3];
    const float* W2 = (const float*)d_in[4];
    const float* b2 = (const float*)d_in[5];
    float* out = (float*)d_out;

    const int n = in_sizes[0] / 5;       // 100000
    const int E = in_sizes[1] / 2;       // 2500000
    const int* src = ei;
    const int* dst = ei + E;
    const int nb = (n + BNODES - 1) >> NB_SHIFT;   // 391

    // unified ws (4B units): [pairs (nb+1)<<13][bcur NBK][deg n][nofs n]
    //                        [dinv n][h2s n][xs 8n]
    int* wsi = (int*)d_ws;
    int*   pairs = wsi;
    int*   bcur  = wsi + ((size_t)(nb + 1) << CAP_SHIFT);
    int*   deg   = bcur + NBK;
    int*   nofs  = deg + n;
    float* dinv  = (float*)(nofs + n);
    float* h2s   = dinv + n;
    float* xs    = h2s + n;

    const int nchunk = (E + CHUNK - 1) / CHUNK;    // 512

    // one-time host-side gate: can GRID blocks be co-resident?
    static int use_coop = -1;
    if (use_coop < 0) {
        int dev = 0, ncu = 0, maxb = 0;
        hipGetDevice(&dev);
        hipDeviceGetAttribute(&ncu, hipDeviceAttributeMultiprocessorCount, dev);
        hipError_t e = hipOccupancyMaxActiveBlocksPerMultiprocessor(
                &maxb, k_fused, PBLK, 0);
        int coop = 0;
        hipDeviceGetAttribute(&coop, hipDeviceAttributeCooperativeLaunch, dev);
        use_coop = (e == hipSuccess && coop && (long)maxb * ncu >= GRID) ? 1 : 0;
    }

    hipMemsetAsync(bcur, 0, (size_t)(NBK + n) * sizeof(int), stream);

    if (use_coop) {
        void* args[] = {(void*)&src, (void*)&dst, (void*)&E, (void*)&x,
                        (void*)&W1, (void*)&b1, (void*)&W2, (void*)&b2,
                        (void*)&out, (void*)&pairs, (void*)&bcur, (void*)&deg,
                        (void*)&h2s, (void*)&xs, (void*)&n, (void*)&nb};
        hipError_t e = hipLaunchCooperativeKernel((const void*)k_fused,
                                                  dim3(GRID), dim3(PBLK),
                                                  args, 0, stream);
        if (e == hipSuccess) return;
        use_coop = 0;                    // launch refused -> permanent fallback
    }

    // fallback: verified R16 pipeline
    const int nagg = (n + 63) / 64;
    k_part<<<nchunk, 512, 0, stream>>>(src, dst, E, bcur, pairs);
    k_sorta<<<nb, 512, 0, stream>>>(pairs, bcur, x, dinv, xs, nofs, deg, n);
    k_sortagg1<<<nb, 512, 0, stream>>>(pairs, bcur, nofs, deg, xs, dinv,
                                       W1, b1, W2, h2s, n);
    k_agg2<<<nagg, 256, 0, stream>>>(pairs, nofs, deg, h2s, dinv, b2, out, n);
}

// Round 3
// 141.756 us; speedup vs baseline: 3.2403x; 3.2403x over previous
//
#include <hip/hip_runtime.h>
#include <hip/hip_cooperative_groups.h>
#include <math.h>

namespace cg = cooperative_groups;

// CascadeGCN R19: cooperative fused kernel, 512-thread blocks, NO global
// atomics. R18 post-mortem: atomicAdd(&deg[dst]) = 2.5M random 64B dirty
// lines = 161 MB WRITE_SIZE storm at 452 GB/s (the entire regression);
// plus 256-thread blocks halved per-phase throughput. R19 computes deg via
// the per-bucket pairs histogram (R16 k_sorta style, coalesced), restores
// 512-thread geometry, and keeps stage2/ofs/cnt LDS-resident through
// layer-2 (no sorted writeback, no agg2 re-read).
// Phases: 0 partition | A hist+scan+xs+sort | B layer1 | C layer2.
// Gate + verified-R16-pipeline fallback retained (launch can't silently fail).

#define NB_SHIFT  8          // 256 nodes per bucket
#define BNODES    256
#define NBK       512        // level-1 key space (nb = 391, padded)
#define CAP       8192       // bucket capacity (mean 6400, +22 sigma)
#define CAP_SHIFT 13
#define CHUNK     4888       // 512 chunks over E=2.5M
#define PBLK      512        // 8 waves (R16 geometry)
#define GRID      512

struct SMemP0 {                       // partition phase: 37520 B
    int sp[CHUNK];                    // packed records (dlow<<24 | src)
    unsigned short sb[CHUNK];         // bucket ids
    int cnt[NBK], ofs[NBK], cur[NBK], gbase[NBK];
};
struct SMemP1 {                       // bucket phases: 36736 B
    int stage2[CAP];                  // node-sorted src ids (persists A->B->C)
    int ofs[BNODES], cnt[BNODES], cur[BNODES];
    float w1[160], bb1[32], w2[32];
};
union SMem { SMemP0 p0; SMemP1 p1; };

__global__ __launch_bounds__(PBLK, 4) void k_fused(
        const int* __restrict__ src, const int* __restrict__ dst, int E,
        const float* __restrict__ x,
        const float* __restrict__ W1, const float* __restrict__ b1,
        const float* __restrict__ W2, const float* __restrict__ b2,
        float* __restrict__ out,
        int* __restrict__ pairs, int* __restrict__ bcur,
        float* __restrict__ h2s, float* __restrict__ xs, int n, int nb) {
    __shared__ SMem sm;
    cg::grid_group grid = cg::this_grid();
    const int tid = threadIdx.x;
    const int blk = blockIdx.x;
    const int nbase = blk << NB_SHIFT;

    // ---------- phase 0: LDS bucket partition (verbatim R16 k_part) ----------
    {
        int base = blk * CHUNK;
        if (base < E) {
            int m = min(CHUNK, E - base);
            sm.p0.cnt[tid] = 0;                       // NBK == PBLK
            __syncthreads();
            for (int i = tid; i < m; i += 2 * PBLK) { // histogram, 2x unrolled
                int i1 = i + PBLK;
                int k0 = dst[base + i] >> NB_SHIFT;
                int k1 = (i1 < m) ? (dst[base + i1] >> NB_SHIFT) : -1;
                atomicAdd(&sm.p0.cnt[k0], 1);
                if (k1 >= 0) atomicAdd(&sm.p0.cnt[k1], 1);
            }
            __syncthreads();
            int v = sm.p0.cnt[tid];                   // exclusive scan, 1/thread
            sm.p0.ofs[tid] = v;
            __syncthreads();
            for (int off = 1; off < NBK; off <<= 1) {
                int u = (tid >= off) ? sm.p0.ofs[tid - off] : 0;
                __syncthreads();
                sm.p0.ofs[tid] += u;
                __syncthreads();
            }
            int pre = sm.p0.ofs[tid] - v;
            sm.p0.ofs[tid] = pre;
            sm.p0.cur[tid] = pre;
            sm.p0.gbase[tid] = (tid << CAP_SHIFT)
                             + (v ? atomicAdd(&bcur[tid], v) : 0);
            __syncthreads();
            // bucket-ordered scatter into LDS (4x unrolled)
            for (int i = tid; i < m; i += 4 * PBLK) {
                int ia = i + PBLK, ib = i + 2 * PBLK, ic = i + 3 * PBLK;
                int s0 = src[base + i], d0 = dst[base + i];
                int s1 = 0, d1 = 0, s2 = 0, d2 = 0, s3 = 0, d3 = 0;
                if (ia < m) { s1 = src[base + ia]; d1 = dst[base + ia]; }
                if (ib < m) { s2 = src[base + ib]; d2 = dst[base + ib]; }
                if (ic < m) { s3 = src[base + ic]; d3 = dst[base + ic]; }
                int b0 = d0 >> NB_SHIFT;
                int p0 = atomicAdd(&sm.p0.cur[b0], 1);
                sm.p0.sp[p0] = ((d0 & (BNODES - 1)) << 24) | s0;
                sm.p0.sb[p0] = (unsigned short)b0;
                if (ia < m) {
                    int b1k = d1 >> NB_SHIFT;
                    int p1 = atomicAdd(&sm.p0.cur[b1k], 1);
                    sm.p0.sp[p1] = ((d1 & (BNODES - 1)) << 24) | s1;
                    sm.p0.sb[p1] = (unsigned short)b1k;
                }
                if (ib < m) {
                    int b2k = d2 >> NB_SHIFT;
                    int p2 = atomicAdd(&sm.p0.cur[b2k], 1);
                    sm.p0.sp[p2] = ((d2 & (BNODES - 1)) << 24) | s2;
                    sm.p0.sb[p2] = (unsigned short)b2k;
                }
                if (ic < m) {
                    int b3k = d3 >> NB_SHIFT;
                    int p3 = atomicAdd(&sm.p0.cur[b3k], 1);
                    sm.p0.sp[p3] = ((d3 & (BNODES - 1)) << 24) | s3;
                    sm.p0.sb[p3] = (unsigned short)b3k;
                }
            }
            __syncthreads();
            for (int i = tid; i < m; i += PBLK) {     // coalesced-run writeout
                int b = sm.p0.sb[i];
                pairs[sm.p0.gbase[b] + (i - sm.p0.ofs[b])] = sm.p0.sp[i];
            }
        }
    }
    grid.sync();   // pairs + bcur complete

    // ---------- phase A: histogram -> deg/nofs/xs, then LDS counting sort ----
    if (blk < nb) {
        int base = blk << CAP_SHIFT;
        int len = min(bcur[blk], CAP);
        if (tid < 160) sm.p1.w1[tid] = W1[tid];
        else if (tid < 192) sm.p1.bb1[tid - 160] = b1[tid - 160];
        else if (tid < 224) sm.p1.w2[tid - 192] = W2[tid - 192];
        if (tid < BNODES) sm.p1.cnt[tid] = 0;
        __syncthreads();
        for (int i = tid; i < len; i += PBLK)         // node histogram
            atomicAdd(&sm.p1.cnt[((unsigned)pairs[base + i]) >> 24], 1);
        __syncthreads();
        int v = (tid < BNODES) ? sm.p1.cnt[tid] : 0;  // scan (first 256 lanes)
        if (tid < BNODES) sm.p1.ofs[tid] = v;
        __syncthreads();
        for (int off = 1; off < BNODES; off <<= 1) {
            int u = (tid < BNODES && tid >= off) ? sm.p1.ofs[tid - off] : 0;
            __syncthreads();
            if (tid < BNODES) sm.p1.ofs[tid] += u;
            __syncthreads();
        }
        if (tid < BNODES) {
            int pre = sm.p1.ofs[tid] - v;             // exclusive
            sm.p1.ofs[tid] = pre;
            sm.p1.cur[tid] = pre;
            int node = nbase + tid;
            if (node < n) {                           // dinv-scaled features
                float di = rsqrtf((float)v + 1.0f);
                const float* xr = x + (size_t)node * 5;
                float* xo = xs + ((size_t)node << 3); // padded row: 8 floats
#pragma unroll
                for (int k = 0; k < 5; ++k) xo[k] = xr[k] * di;
            }
        }
        __syncthreads();
        // counting-sort scatter into stage2 (4x unrolled)
        for (int i = tid; i < len; i += 4 * PBLK) {
            int ia = i + PBLK, ib = i + 2 * PBLK, ic = i + 3 * PBLK;
            int v0 = pairs[base + i];
            int v1 = (ia < len) ? pairs[base + ia] : -1;
            int v2 = (ib < len) ? pairs[base + ib] : -1;
            int v3 = (ic < len) ? pairs[base + ic] : -1;
            int p0 = atomicAdd(&sm.p1.cur[((unsigned)v0) >> 24], 1);
            sm.p1.stage2[p0] = v0 & 0x00FFFFFF;
            if (v1 != -1) {
                int p1 = atomicAdd(&sm.p1.cur[((unsigned)v1) >> 24], 1);
                sm.p1.stage2[p1] = v1 & 0x00FFFFFF;
            }
            if (v2 != -1) {
                int p2 = atomicAdd(&sm.p1.cur[((unsigned)v2) >> 24], 1);
                sm.p1.stage2[p2] = v2 & 0x00FFFFFF;
            }
            if (v3 != -1) {
                int p3 = atomicAdd(&sm.p1.cur[((unsigned)v3) >> 24], 1);
                sm.p1.stage2[p3] = v3 & 0x00FFFFFF;
            }
        }
    }
    grid.sync();   // xs complete everywhere (cross-bucket gathers ahead)

    // ---------- phase B: layer-1 aggregation from LDS-resident stage2 --------
    if (blk < nb) {
        int t2 = tid >> 1, half = tid & 1;            // 2 threads/node
        int node = nbase + t2;
        if (node < n) {                               // no return: sync follows
            int beg = sm.p1.ofs[t2], dg = sm.p1.cnt[t2];
            float a0 = 0.f, a1 = 0.f, a2 = 0.f, a3 = 0.f, a4 = 0.f;
            if (!half) {                              // self-loop term
                const float* xo = xs + ((size_t)node << 3);
                a0 = xo[0]; a1 = xo[1]; a2 = xo[2]; a3 = xo[3]; a4 = xo[4];
            }
            for (int e = beg + half; e < beg + dg; e += 2) {
                int s = sm.p1.stage2[e];
                const float* xr = xs + ((size_t)s << 3);
                float4 q = *(const float4*)xr;
                float q4 = xr[4];
                a0 += q.x; a1 += q.y; a2 += q.z; a3 += q.w; a4 += q4;
            }
            a0 += __shfl_xor(a0, 1); a1 += __shfl_xor(a1, 1);
            a2 += __shfl_xor(a2, 1); a3 += __shfl_xor(a3, 1);
            a4 += __shfl_xor(a4, 1);
            if (!half) {
                float di = rsqrtf((float)dg + 1.0f);
                a0 *= di; a1 *= di; a2 *= di; a3 *= di; a4 *= di;
                float sum = 0.f;
#pragma unroll
                for (int c = 0; c < 32; ++c) {
                    float z = sm.p1.bb1[c] + a0 * sm.p1.w1[c]
                            + a1 * sm.p1.w1[32 + c] + a2 * sm.p1.w1[64 + c]
                            + a3 * sm.p1.w1[96 + c] + a4 * sm.p1.w1[128 + c];
                    sum += fmaxf(z, 0.f) * sm.p1.w2[c];
                }
                h2s[node] = sum * di;                 // pre-scale by src dinv
            }
        }
    }
    grid.sync();   // h2s complete

    // ---------- phase C: layer-2 from LDS-resident stage2 --------------------
    if (blk < nb) {
        int t2 = tid >> 1, half = tid & 1;
        int node = nbase + t2;
        if (node >= n) return;                        // last phase: return ok
        int beg = sm.p1.ofs[t2], dg = sm.p1.cnt[t2];
        float a = 0.f;
        for (int e = beg + half; e < beg + dg; e += 2)
            a += h2s[sm.p1.stage2[e]];
        a += __shfl_xor(a, 1);
        if (!half) {
            float di = rsqrtf((float)dg + 1.0f);
            float vv = di * (a + h2s[node]) + b2[0];
            out[node] = 1.0f / (1.0f + __expf(-vv));
        }
    }
}

// ===================== fallback: verified R16 pipeline =====================

__global__ __launch_bounds__(512) void k_part(const int* __restrict__ src,
                                              const int* __restrict__ dst, int E,
                                              int* __restrict__ bcur,
                                              int* __restrict__ pairs) {
    __shared__ int sp[CHUNK];
    __shared__ unsigned short sb[CHUNK];
    __shared__ int cnt[NBK], ofs[NBK], cur[NBK], gbase[NBK];
    int tid = threadIdx.x;
    int base = blockIdx.x * CHUNK;
    int m = min(CHUNK, E - base);

    if (tid < NBK) cnt[tid] = 0;
    __syncthreads();
    for (int i = tid; i < m; i += 2 * 512) {
        int i1 = i + 512;
        int k0 = dst[base + i] >> NB_SHIFT;
        int k1 = (i1 < m) ? (dst[base + i1] >> NB_SHIFT) : -1;
        atomicAdd(&cnt[k0], 1);
        if (k1 >= 0) atomicAdd(&cnt[k1], 1);
    }
    __syncthreads();
    int v = cnt[tid];
    ofs[tid] = v;
    __syncthreads();
    for (int off = 1; off < NBK; off <<= 1) {
        int u = (tid >= off) ? ofs[tid - off] : 0;
        __syncthreads();
        ofs[tid] += u;
        __syncthreads();
    }
    int pre = ofs[tid] - v;
    ofs[tid] = pre;
    cur[tid] = pre;
    gbase[tid] = (tid << CAP_SHIFT) + (v ? atomicAdd(&bcur[tid], v) : 0);
    __syncthreads();
    for (int i = tid; i < m; i += 4 * 512) {
        int ia = i + 512, ib = i + 1024, ic = i + 1536;
        int s0 = src[base + i], d0 = dst[base + i];
        int s1 = 0, d1 = 0, s2 = 0, d2 = 0, s3 = 0, d3 = 0;
        if (ia < m) { s1 = src[base + ia]; d1 = dst[base + ia]; }
        if (ib < m) { s2 = src[base + ib]; d2 = dst[base + ib]; }
        if (ic < m) { s3 = src[base + ic]; d3 = dst[base + ic]; }
        int b0 = d0 >> NB_SHIFT;
        int p0 = atomicAdd(&cur[b0], 1);
        sp[p0] = ((d0 & (BNODES - 1)) << 24) | s0;
        sb[p0] = (unsigned short)b0;
        if (ia < m) {
            int b1 = d1 >> NB_SHIFT;
            int p1 = atomicAdd(&cur[b1], 1);
            sp[p1] = ((d1 & (BNODES - 1)) << 24) | s1;
            sb[p1] = (unsigned short)b1;
        }
        if (ib < m) {
            int b2 = d2 >> NB_SHIFT;
            int p2 = atomicAdd(&cur[b2], 1);
            sp[p2] = ((d2 & (BNODES - 1)) << 24) | s2;
            sb[p2] = (unsigned short)b2;
        }
        if (ic < m) {
            int b3 = d3 >> NB_SHIFT;
            int p3 = atomicAdd(&cur[b3], 1);
            sp[p3] = ((d3 & (BNODES - 1)) << 24) | s3;
            sb[p3] = (unsigned short)b3;
        }
    }
    __syncthreads();
    for (int i = tid; i < m; i += 512) {
        int b = sb[i];
        pairs[gbase[b] + (i - ofs[b])] = sp[i];
    }
}

__global__ __launch_bounds__(512) void k_sorta(const int* __restrict__ pairs,
                                               const int* __restrict__ bcur,
                                               const float* __restrict__ x,
                                               float* __restrict__ dinv,
                                               float* __restrict__ xs,
                                               int* __restrict__ nofs,
                                               int* __restrict__ deg, int n) {
    __shared__ int cnt[BNODES], scn[BNODES];
    int tid = threadIdx.x;
    int b = blockIdx.x;
    int base = b << CAP_SHIFT;
    int len = min(bcur[b], CAP);

    if (tid < BNODES) cnt[tid] = 0;
    __syncthreads();
    for (int i = tid; i < len; i += 512)
        atomicAdd(&cnt[((unsigned)pairs[base + i]) >> 24], 1);
    __syncthreads();
    int v = (tid < BNODES) ? cnt[tid] : 0;
    if (tid < BNODES) scn[tid] = v;
    __syncthreads();
    for (int off = 1; off < BNODES; off <<= 1) {
        int u = (tid < BNODES && tid >= off) ? scn[tid - off] : 0;
        __syncthreads();
        if (tid < BNODES) scn[tid] += u;
        __syncthreads();
    }
    if (tid < BNODES) {
        int node = (b << NB_SHIFT) + tid;
        if (node < n) {
            nofs[node] = base + scn[tid] - v;
            deg[node] = v;
            float di = rsqrtf((float)v + 1.0f);
            dinv[node] = di;
            const float* xr = x + (size_t)node * 5;
            float* xo = xs + ((size_t)node << 3);
#pragma unroll
            for (int k = 0; k < 5; ++k) xo[k] = xr[k] * di;
        }
    }
}

__global__ __launch_bounds__(512) void k_sortagg1(int* __restrict__ pairs,
                                                  const int* __restrict__ bcur,
                                                  const int* __restrict__ nofs,
                                                  const int* __restrict__ deg,
                                                  const float* __restrict__ xs,
                                                  const float* __restrict__ dinv,
                                                  const float* __restrict__ W1,
                                                  const float* __restrict__ b1,
                                                  const float* __restrict__ W2,
                                                  float* __restrict__ h2s, int n) {
    __shared__ int stage2[CAP];
    __shared__ int ofs[BNODES], cnt[BNODES], cur[BNODES];
    __shared__ float w1[160], bb1[32], w2[32];
    int tid = threadIdx.x;
    int b = blockIdx.x;
    int nbase = b << NB_SHIFT;
    int base = b << CAP_SHIFT;
    int len = min(bcur[b], CAP);

    if (tid < 160) w1[tid] = W1[tid];
    else if (tid < 192) bb1[tid - 160] = b1[tid - 160];
    else if (tid < 224) w2[tid - 192] = W2[tid - 192];
    if (tid < BNODES) {
        int node = nbase + tid;
        int o = 0, c = 0;
        if (node < n) { o = nofs[node] - base; c = deg[node]; }
        ofs[tid] = o; cnt[tid] = c; cur[tid] = o;
    }
    __syncthreads();
    for (int i = tid; i < len; i += 2048) {
        int ia = i + 512, ib = i + 1024, ic = i + 1536;
        int v0 = pairs[base + i];
        int v1 = (ia < len) ? pairs[base + ia] : -1;
        int v2 = (ib < len) ? pairs[base + ib] : -1;
        int v3 = (ic < len) ? pairs[base + ic] : -1;
        int p0 = atomicAdd(&cur[((unsigned)v0) >> 24], 1);
        stage2[p0] = v0 & 0x00FFFFFF;
        if (v1 != -1) {
            int p1 = atomicAdd(&cur[((unsigned)v1) >> 24], 1);
            stage2[p1] = v1 & 0x00FFFFFF;
        }
        if (v2 != -1) {
            int p2 = atomicAdd(&cur[((unsigned)v2) >> 24], 1);
            stage2[p2] = v2 & 0x00FFFFFF;
        }
        if (v3 != -1) {
            int p3 = atomicAdd(&cur[((unsigned)v3) >> 24], 1);
            stage2[p3] = v3 & 0x00FFFFFF;
        }
    }
    __syncthreads();
    {
        int len4 = len >> 2;
        const int4* s4 = (const int4*)stage2;
        int4* p4 = (int4*)(pairs + base);
        for (int i = tid; i < len4; i += 512) p4[i] = s4[i];
        for (int i = (len4 << 2) + tid; i < len; i += 512)
            pairs[base + i] = stage2[i];
    }
    int t2 = tid >> 1, half = tid & 1;
    int node = nbase + t2;
    if (node >= n) return;
    int beg = ofs[t2], dg = cnt[t2];
    float a0 = 0.f, a1 = 0.f, a2 = 0.f, a3 = 0.f, a4 = 0.f;
    if (!half) {
        const float* xo = xs + ((size_t)node << 3);
        a0 = xo[0]; a1 = xo[1]; a2 = xo[2]; a3 = xo[3]; a4 = xo[4];
    }
    for (int e = beg + half; e < beg + dg; e += 2) {
        int s = stage2[e];
        const float* xr = xs + ((size_t)s << 3);
        float4 q = *(const float4*)xr;
        float q4 = xr[4];
        a0 += q.x; a1 += q.y; a2 += q.z; a3 += q.w; a4 += q4;
    }
    a0 += __shfl_xor(a0, 1); a1 += __shfl_xor(a1, 1); a2 += __shfl_xor(a2, 1);
    a3 += __shfl_xor(a3, 1); a4 += __shfl_xor(a4, 1);
    if (half) return;
    float di = dinv[node];
    a0 *= di; a1 *= di; a2 *= di; a3 *= di; a4 *= di;
    float sum = 0.f;
#pragma unroll
    for (int c = 0; c < 32; ++c) {
        float z = bb1[c] + a0 * w1[c] + a1 * w1[32 + c] + a2 * w1[64 + c]
                         + a3 * w1[96 + c] + a4 * w1[128 + c];
        sum += fmaxf(z, 0.f) * w2[c];
    }
    h2s[node] = sum * di;
}

__global__ __launch_bounds__(256) void k_agg2(const int* __restrict__ pairs,
                                              const int* __restrict__ nofs,
                                              const int* __restrict__ deg,
                                              const float* __restrict__ h2s,
                                              const float* __restrict__ dinv,
                                              const float* __restrict__ b2,
                                              float* __restrict__ out, int n) {
    int tid = threadIdx.x;
    int node = blockIdx.x * 64 + (tid >> 2);
    int q = tid & 3;
    if (node >= n) return;
    int beg = nofs[node], dg = deg[node];
    float a = 0.f;
    for (int e = beg + q; e < beg + dg; e += 4) a += h2s[pairs[e]];
    a += __shfl_xor(a, 1);
    a += __shfl_xor(a, 2);
    if (q) return;
    float v = dinv[node] * (a + h2s[node]) + b2[0];
    out[node] = 1.0f / (1.0f + __expf(-v));
}

extern "C" void kernel_launch(void* const* d_in, const int* in_sizes, int n_in,
                              void* d_out, int out_size, void* d_ws, size_t ws_size,
                              hipStream_t stream) {
    const float* x  = (const float*)d_in[0];
    const int*   ei = (const int*)d_in[1];
    const float* W1 = (const float*)d_in[2];
    const float* b1 = (const float*)d_in[3];
    const float* W2 = (const float*)d_in[4];
    const float* b2 = (const float*)d_in[5];
    float* out = (float*)d_out;

    const int n = in_sizes[0] / 5;       // 100000
    const int E = in_sizes[1] / 2;       // 2500000
    const int* src = ei;
    const int* dst = ei + E;
    const int nb = (n + BNODES - 1) >> NB_SHIFT;   // 391

    // unified ws (4B units): [pairs (nb+1)<<13][bcur NBK][deg n][nofs n]
    //                        [dinv n][h2s n][xs 8n]
    int* wsi = (int*)d_ws;
    int*   pairs = wsi;
    int*   bcur  = wsi + ((size_t)(nb + 1) << CAP_SHIFT);
    int*   deg   = bcur + NBK;
    int*   nofs  = deg + n;
    float* dinv  = (float*)(nofs + n);
    float* h2s   = dinv + n;
    float* xs    = h2s + n;

    const int nchunk = (E + CHUNK - 1) / CHUNK;    // 512
    const int g = nchunk > nb ? nchunk : nb;       // 512

    // one-time host-side gate: can g blocks be co-resident?
    static int use_coop = -1;
    if (use_coop < 0) {
        int dev = 0, ncu = 0, maxb = 0;
        hipGetDevice(&dev);
        hipDeviceGetAttribute(&ncu, hipDeviceAttributeMultiprocessorCount, dev);
        hipError_t e = hipOccupancyMaxActiveBlocksPerMultiprocessor(
                &maxb, k_fused, PBLK, 0);
        int coop = 0;
        hipDeviceGetAttribute(&coop, hipDeviceAttributeCooperativeLaunch, dev);
        use_coop = (e == hipSuccess && coop && (long)maxb * ncu >= g) ? 1 : 0;
    }

    hipMemsetAsync(bcur, 0, NBK * sizeof(int), stream);

    if (use_coop) {
        void* args[] = {(void*)&src, (void*)&dst, (void*)&E, (void*)&x,
                        (void*)&W1, (void*)&b1, (void*)&W2, (void*)&b2,
                        (void*)&out, (void*)&pairs, (void*)&bcur,
                        (void*)&h2s, (void*)&xs, (void*)&n, (void*)&nb};
        hipError_t e = hipLaunchCooperativeKernel((const void*)k_fused,
                                                  dim3(g), dim3(PBLK),
                                                  args, 0, stream);
        if (e == hipSuccess) return;
        use_coop = 0;                    // launch refused -> permanent fallback
    }

    // fallback: verified R16 pipeline
    const int nagg = (n + 63) / 64;
    k_part<<<nchunk, 512, 0, stream>>>(src, dst, E, bcur, pairs);
    k_sorta<<<nb, 512, 0, stream>>>(pairs, bcur, x, dinv, xs, nofs, deg, n);
    k_sortagg1<<<nb, 512, 0, stream>>>(pairs, bcur, nofs, deg, xs, dinv,
                                       W1, b1, W2, h2s, n);
    k_agg2<<<nagg, 256, 0, stream>>>(pairs, nofs, deg, h2s, dinv, b2, out, n);
}